// Round 9
// baseline (768.678 us; speedup 1.0000x reference)
//
#include <hip/hip_runtime.h>
#include <hip/hip_bf16.h>

#define EPSBN 1e-3f

constexpr int kW   = 64;
constexpr int kF   = 120;
constexpr int kC1  = 192;   // 3*W
constexpr int kN2  = 240;
constexpr int kOut = 121;
constexpr int BTOT = 16384;

// ======================= Kernel A: conv + tanh -> combined =======================
// R6/R7 version (known 'a' term). Launched 3x this round for timing decomposition.
__global__ __launch_bounds__(256, 4) void conv_kernel(
    const float* __restrict__ x,
    const float* __restrict__ conv_w, const float* __restrict__ conv_b,
    float* __restrict__ combined)
{
  __shared__ float comb[16 * kC1];   // 12.3 KB

  const int tid  = threadIdx.x;
  const int lane = tid & 63;
  const int wid  = tid >> 6;
  const int b0   = blockIdx.x * 16;

  const int row  = wid * 4 + (lane >> 4);   // 0..15
  const int wloc = lane & 15;

  for (int wc = 0; wc < 4; ++wc) {
    const int w = wc * 16 + wloc;
    const float* xr  = x + ((size_t)(b0 + row) * kW + w) * kF;
    const float* cwp = conv_w + (size_t)w * 360;   // [f*3+k]
    float a0 = 0.f, a1 = 0.f, a2 = 0.f;
    for (int t = 0; t < 30; ++t) {
      float4 xv = *reinterpret_cast<const float4*>(xr + 4 * t);
      float4 c0 = *reinterpret_cast<const float4*>(cwp + 12 * t);
      float4 c1 = *reinterpret_cast<const float4*>(cwp + 12 * t + 4);
      float4 c2 = *reinterpret_cast<const float4*>(cwp + 12 * t + 8);
      a0 += xv.x * c0.x + xv.y * c0.w + xv.z * c1.z + xv.w * c2.y;
      a1 += xv.x * c0.y + xv.y * c1.x + xv.z * c1.w + xv.w * c2.z;
      a2 += xv.x * c0.z + xv.y * c1.y + xv.z * c2.x + xv.w * c2.w;
    }
    comb[row * kC1 + 3 * w + 0] = tanhf(a0 + conv_b[3 * w + 0]);
    comb[row * kC1 + 3 * w + 1] = tanhf(a1 + conv_b[3 * w + 1]);
    comb[row * kC1 + 3 * w + 2] = tanhf(a2 + conv_b[3 * w + 2]);
  }
  __syncthreads();

  float4* dst = reinterpret_cast<float4*>(combined + (size_t)b0 * kC1);
  const float4* srcv = reinterpret_cast<const float4*>(comb);
  #pragma unroll
  for (int q = 0; q < 3; ++q) {
    int idx = q * 256 + tid;
    dst[idx] = srcv[idx];
  }
}

// ======================= Kernel B: MLP heads (UNCHANGED from R7/R8) =======================
__global__ __launch_bounds__(64, 4) void mlp_kernel(
    const float* __restrict__ combined,
    const float* __restrict__ e_g1, const float* __restrict__ e_b1,
    const float* __restrict__ e_m1, const float* __restrict__ e_v1,
    const float* __restrict__ e_d1_w, const float* __restrict__ e_d1_b,
    const float* __restrict__ e_g2, const float* __restrict__ e_b2,
    const float* __restrict__ e_m2, const float* __restrict__ e_v2,
    const float* __restrict__ e_d2_w, const float* __restrict__ e_d2_b,
    const float* __restrict__ e_d3_w, const float* __restrict__ e_d3_b,
    const float* __restrict__ b_g1, const float* __restrict__ b_b1,
    const float* __restrict__ b_m1, const float* __restrict__ b_v1,
    const float* __restrict__ b_d1_w, const float* __restrict__ b_d1_b,
    const float* __restrict__ b_g2, const float* __restrict__ b_b2,
    const float* __restrict__ b_m2, const float* __restrict__ b_v2,
    const float* __restrict__ b_d2_w, const float* __restrict__ b_d2_b,
    const float* __restrict__ b_d3_w, const float* __restrict__ b_d3_b,
    float* __restrict__ out)
{
  __shared__ __align__(16) float A[4 * kN2];   // 3.84 KB

  const int lane = threadIdx.x;   // 0..63
  const int r0g  = blockIdx.x * 4;
  #define AR(rr) (A + (size_t)(rr) * kN2)

  #pragma unroll
  for (int cc = 0; cc < 3; ++cc) {
    int i = cc * 64 + lane;
    float s = e_g1[i] * rsqrtf(e_v1[i] + EPSBN);
    float t = e_b1[i] - e_m1[i] * s;
    #pragma unroll
    for (int rr = 0; rr < 4; ++rr)
      AR(rr)[i] = combined[(size_t)(r0g + rr) * kC1 + i] * s + t;
  }
  __syncthreads();

  {
    float acc[4][3];
    #pragma unroll
    for (int rr = 0; rr < 4; ++rr) { acc[rr][0] = acc[rr][1] = acc[rr][2] = 0.f; }
    #pragma unroll 3
    for (int i = 0; i < kC1; i += 4) {
      float4 v[4];
      #pragma unroll
      for (int rr = 0; rr < 4; ++rr) v[rr] = *reinterpret_cast<const float4*>(AR(rr) + i);
      #pragma unroll
      for (int io = 0; io < 4; ++io) {
        const float* wp = e_d1_w + (size_t)(i + io) * kC1 + lane;
        float w0 = wp[0], w1 = wp[64], w2 = wp[128];
        #pragma unroll
        for (int rr = 0; rr < 4; ++rr) {
          float xv = reinterpret_cast<const float*>(&v[rr])[io];
          acc[rr][0] = fmaf(xv, w0, acc[rr][0]);
          acc[rr][1] = fmaf(xv, w1, acc[rr][1]);
          acc[rr][2] = fmaf(xv, w2, acc[rr][2]);
        }
      }
    }
    __syncthreads();
    #pragma unroll
    for (int c = 0; c < 3; ++c) {
      int j = c * 64 + lane;
      float s  = e_g2[j] * rsqrtf(e_v2[j] + EPSBN);
      float t  = e_b2[j] - e_m2[j] * s;
      float bs = e_d1_b[j];
      #pragma unroll
      for (int rr = 0; rr < 4; ++rr)
        AR(rr)[j] = tanhf(acc[rr][c] + bs) * s + t;
    }
  }
  __syncthreads();

  {
    const bool m3 = (lane < 48);
    float acc[4][4];
    #pragma unroll
    for (int rr = 0; rr < 4; ++rr) { acc[rr][0]=acc[rr][1]=acc[rr][2]=acc[rr][3]=0.f; }
    #pragma unroll 3
    for (int i = 0; i < kC1; i += 4) {
      float4 v[4];
      #pragma unroll
      for (int rr = 0; rr < 4; ++rr) v[rr] = *reinterpret_cast<const float4*>(AR(rr) + i);
      #pragma unroll
      for (int io = 0; io < 4; ++io) {
        const float* wp = e_d2_w + (size_t)(i + io) * kN2 + lane;
        float w0 = wp[0], w1 = wp[64], w2 = wp[128];
        float w3 = m3 ? wp[192] : 0.f;
        #pragma unroll
        for (int rr = 0; rr < 4; ++rr) {
          float xv = reinterpret_cast<const float*>(&v[rr])[io];
          acc[rr][0] = fmaf(xv, w0, acc[rr][0]);
          acc[rr][1] = fmaf(xv, w1, acc[rr][1]);
          acc[rr][2] = fmaf(xv, w2, acc[rr][2]);
          acc[rr][3] = fmaf(xv, w3, acc[rr][3]);
        }
      }
    }
    __syncthreads();
    #pragma unroll
    for (int c = 0; c < 4; ++c) {
      int j = c * 64 + lane;
      if (c < 3 || m3) {
        float bs = e_d2_b[j];
        #pragma unroll
        for (int rr = 0; rr < 4; ++rr)
          AR(rr)[j] = acc[rr][c] + bs;
      }
    }
  }
  __syncthreads();

  {
    const bool m56 = (lane < 56);
    float acc[4][2];
    #pragma unroll
    for (int rr = 0; rr < 4; ++rr) { acc[rr][0] = acc[rr][1] = 0.f; }
    #pragma unroll 3
    for (int i = 0; i < kN2; i += 4) {
      float4 v[4];
      #pragma unroll
      for (int rr = 0; rr < 4; ++rr) v[rr] = *reinterpret_cast<const float4*>(AR(rr) + i);
      #pragma unroll
      for (int io = 0; io < 4; ++io) {
        const float* wp = e_d3_w + (size_t)(i + io) * 120 + lane;
        float w0 = wp[0];
        float w1 = m56 ? wp[64] : 0.f;
        #pragma unroll
        for (int rr = 0; rr < 4; ++rr) {
          float xv = reinterpret_cast<const float*>(&v[rr])[io];
          acc[rr][0] = fmaf(xv, w0, acc[rr][0]);
          acc[rr][1] = fmaf(xv, w1, acc[rr][1]);
        }
      }
    }
    #pragma unroll
    for (int c = 0; c < 2; ++c) {
      int j = c * 64 + lane;
      if (j < 120) {
        float bs = e_d3_b[j];
        #pragma unroll
        for (int rr = 0; rr < 4; ++rr)
          out[(size_t)(r0g + rr) * kOut + j] = acc[rr][c] + bs;
      }
    }
  }
  __syncthreads();

  #pragma unroll
  for (int cc = 0; cc < 3; ++cc) {
    int i = cc * 64 + lane;
    float s = b_g1[i] * rsqrtf(b_v1[i] + EPSBN);
    float t = b_b1[i] - b_m1[i] * s;
    #pragma unroll
    for (int rr = 0; rr < 4; ++rr)
      AR(rr)[i] = combined[(size_t)(r0g + rr) * kC1 + i] * s + t;
  }
  __syncthreads();

  {
    float acc[4] = {0.f, 0.f, 0.f, 0.f};
    #pragma unroll 3
    for (int i = 0; i < kC1; i += 4) {
      float4 v[4];
      #pragma unroll
      for (int rr = 0; rr < 4; ++rr) v[rr] = *reinterpret_cast<const float4*>(AR(rr) + i);
      #pragma unroll
      for (int io = 0; io < 4; ++io) {
        float w0 = b_d1_w[(size_t)(i + io) * 64 + lane];
        #pragma unroll
        for (int rr = 0; rr < 4; ++rr) {
          float xv = reinterpret_cast<const float*>(&v[rr])[io];
          acc[rr] = fmaf(xv, w0, acc[rr]);
        }
      }
    }
    __syncthreads();
    float s  = b_g2[lane] * rsqrtf(b_v2[lane] + EPSBN);
    float t  = b_b2[lane] - b_m2[lane] * s;
    float bs = b_d1_b[lane];
    #pragma unroll
    for (int rr = 0; rr < 4; ++rr)
      AR(rr)[lane] = tanhf(acc[rr] + bs) * s + t;
  }
  __syncthreads();

  {
    const bool m32 = (lane < 32);
    float acc[4] = {0.f, 0.f, 0.f, 0.f};
    #pragma unroll
    for (int i = 0; i < 64; i += 4) {
      float4 v[4];
      #pragma unroll
      for (int rr = 0; rr < 4; ++rr) v[rr] = *reinterpret_cast<const float4*>(AR(rr) + i);
      #pragma unroll
      for (int io = 0; io < 4; ++io) {
        float w0 = m32 ? b_d2_w[(size_t)(i + io) * 32 + lane] : 0.f;
        #pragma unroll
        for (int rr = 0; rr < 4; ++rr) {
          float xv = reinterpret_cast<const float*>(&v[rr])[io];
          acc[rr] = fmaf(xv, w0, acc[rr]);
        }
      }
    }
    __syncthreads();
    if (m32) {
      float bs = b_d2_b[lane];
      #pragma unroll
      for (int rr = 0; rr < 4; ++rr)
        AR(rr)[lane] = tanhf(acc[rr] + bs);
    }
  }
  __syncthreads();

  if (lane < 4) {
    int rr = lane;
    float acc = b_d3_b[0];
    #pragma unroll
    for (int i = 0; i < 32; ++i)
      acc = fmaf(AR(rr)[i], b_d3_w[i], acc);
    out[(size_t)(r0g + rr) * kOut + 120] = 1.f / (1.f + expf(-acc));
  }
  #undef AR
}

// ======================= Fallback: round-5 fused kernel (known-correct) =======================
constexpr int CSTR = 193;
__global__ __launch_bounds__(64, 4) void fused_blink_fb(
    const float* __restrict__ x,
    const float* __restrict__ conv_w, const float* __restrict__ conv_b,
    const float* __restrict__ e_g1, const float* __restrict__ e_b1,
    const float* __restrict__ e_m1, const float* __restrict__ e_v1,
    const float* __restrict__ e_d1_w, const float* __restrict__ e_d1_b,
    const float* __restrict__ e_g2, const float* __restrict__ e_b2,
    const float* __restrict__ e_m2, const float* __restrict__ e_v2,
    const float* __restrict__ e_d2_w, const float* __restrict__ e_d2_b,
    const float* __restrict__ e_d3_w, const float* __restrict__ e_d3_b,
    const float* __restrict__ b_g1, const float* __restrict__ b_b1,
    const float* __restrict__ b_m1, const float* __restrict__ b_v1,
    const float* __restrict__ b_d1_w, const float* __restrict__ b_d1_b,
    const float* __restrict__ b_g2, const float* __restrict__ b_b2,
    const float* __restrict__ b_m2, const float* __restrict__ b_v2,
    const float* __restrict__ b_d2_w, const float* __restrict__ b_d2_b,
    const float* __restrict__ b_d3_w, const float* __restrict__ b_d3_b,
    float* __restrict__ out)
{
  __shared__ float comb[4 * CSTR];
  __shared__ __align__(16) float Ab[4 * kN2];
  __shared__ __align__(16) float Bb[4 * kN2];
  const int lane = threadIdx.x;
  const int b0   = blockIdx.x * 4;
  {
    const int rcv = lane >> 4, wloc = lane & 15;
    for (int wc = 0; wc < 4; ++wc) {
      const int w = wc * 16 + wloc;
      const float* xr  = x + ((size_t)(b0 + rcv) * kW + w) * kF;
      const float* cwp = conv_w + (size_t)w * 360;
      float a0 = 0.f, a1 = 0.f, a2 = 0.f;
      for (int t = 0; t < 30; ++t) {
        float4 xv = *reinterpret_cast<const float4*>(xr + 4 * t);
        float4 c0 = *reinterpret_cast<const float4*>(cwp + 12 * t);
        float4 c1 = *reinterpret_cast<const float4*>(cwp + 12 * t + 4);
        float4 c2 = *reinterpret_cast<const float4*>(cwp + 12 * t + 8);
        a0 += xv.x * c0.x + xv.y * c0.w + xv.z * c1.z + xv.w * c2.y;
        a1 += xv.x * c0.y + xv.y * c1.x + xv.z * c1.w + xv.w * c2.z;
        a2 += xv.x * c0.z + xv.y * c1.y + xv.z * c2.x + xv.w * c2.w;
      }
      comb[rcv * CSTR + 3 * w + 0] = tanhf(a0 + conv_b[3 * w + 0]);
      comb[rcv * CSTR + 3 * w + 1] = tanhf(a1 + conv_b[3 * w + 1]);
      comb[rcv * CSTR + 3 * w + 2] = tanhf(a2 + conv_b[3 * w + 2]);
    }
  }
  __syncthreads();
  #define AR(rr) (Ab + (size_t)(rr) * kN2)
  #define BR(rr) (Bb + (size_t)(rr) * kN2)
  #pragma unroll
  for (int q = 0; q < 12; ++q) {
    int rr = q / 3, cc = q % 3;
    int i = cc * 64 + lane;
    float s = e_g1[i] * rsqrtf(e_v1[i] + EPSBN);
    AR(rr)[i] = comb[rr * CSTR + i] * s + (e_b1[i] - e_m1[i] * s);
  }
  __syncthreads();
  {
    float acc[4][3];
    #pragma unroll
    for (int rr = 0; rr < 4; ++rr) { acc[rr][0]=acc[rr][1]=acc[rr][2]=0.f; }
    for (int i = 0; i < kC1; i += 4) {
      float4 v[4];
      #pragma unroll
      for (int rr = 0; rr < 4; ++rr) v[rr] = *reinterpret_cast<const float4*>(AR(rr) + i);
      #pragma unroll
      for (int io = 0; io < 4; ++io) {
        const float* wp = e_d1_w + (size_t)(i + io) * kC1 + lane;
        float w0 = wp[0], w1 = wp[64], w2 = wp[128];
        #pragma unroll
        for (int rr = 0; rr < 4; ++rr) {
          float xv = reinterpret_cast<const float*>(&v[rr])[io];
          acc[rr][0] = fmaf(xv, w0, acc[rr][0]);
          acc[rr][1] = fmaf(xv, w1, acc[rr][1]);
          acc[rr][2] = fmaf(xv, w2, acc[rr][2]);
        }
      }
    }
    #pragma unroll
    for (int c = 0; c < 3; ++c) {
      int j = c * 64 + lane;
      float s  = e_g2[j] * rsqrtf(e_v2[j] + EPSBN);
      float t  = e_b2[j] - e_m2[j] * s;
      float bs = e_d1_b[j];
      #pragma unroll
      for (int rr = 0; rr < 4; ++rr)
        BR(rr)[j] = tanhf(acc[rr][c] + bs) * s + t;
    }
  }
  __syncthreads();
  {
    const bool m3 = (lane < 48);
    float acc[4][4];
    #pragma unroll
    for (int rr = 0; rr < 4; ++rr) { acc[rr][0]=acc[rr][1]=acc[rr][2]=acc[rr][3]=0.f; }
    for (int i = 0; i < kC1; i += 4) {
      float4 v[4];
      #pragma unroll
      for (int rr = 0; rr < 4; ++rr) v[rr] = *reinterpret_cast<const float4*>(BR(rr) + i);
      #pragma unroll
      for (int io = 0; io < 4; ++io) {
        const float* wp = e_d2_w + (size_t)(i + io) * kN2 + lane;
        float w0 = wp[0], w1 = wp[64], w2 = wp[128];
        float w3 = m3 ? wp[192] : 0.f;
        #pragma unroll
        for (int rr = 0; rr < 4; ++rr) {
          float xv = reinterpret_cast<const float*>(&v[rr])[io];
          acc[rr][0] = fmaf(xv, w0, acc[rr][0]);
          acc[rr][1] = fmaf(xv, w1, acc[rr][1]);
          acc[rr][2] = fmaf(xv, w2, acc[rr][2]);
          acc[rr][3] = fmaf(xv, w3, acc[rr][3]);
        }
      }
    }
    #pragma unroll
    for (int c = 0; c < 4; ++c) {
      int j = c * 64 + lane;
      if (c < 3 || m3) {
        float bs = e_d2_b[j];
        #pragma unroll
        for (int rr = 0; rr < 4; ++rr)
          AR(rr)[j] = acc[rr][c] + bs;
      }
    }
  }
  __syncthreads();
  #pragma unroll
  for (int q = 0; q < 12; ++q) {
    int rr = q / 3, cc = q % 3;
    int i = cc * 64 + lane;
    float s = b_g1[i] * rsqrtf(b_v1[i] + EPSBN);
    BR(rr)[i] = comb[rr * CSTR + i] * s + (b_b1[i] - b_m1[i] * s);
  }
  {
    const bool m56 = (lane < 56);
    float acc[4][2];
    #pragma unroll
    for (int rr = 0; rr < 4; ++rr) { acc[rr][0]=acc[rr][1]=0.f; }
    for (int i = 0; i < kN2; i += 4) {
      float4 v[4];
      #pragma unroll
      for (int rr = 0; rr < 4; ++rr) v[rr] = *reinterpret_cast<const float4*>(AR(rr) + i);
      #pragma unroll
      for (int io = 0; io < 4; ++io) {
        const float* wp = e_d3_w + (size_t)(i + io) * 120 + lane;
        float w0 = wp[0];
        float w1 = m56 ? wp[64] : 0.f;
        #pragma unroll
        for (int rr = 0; rr < 4; ++rr) {
          float xv = reinterpret_cast<const float*>(&v[rr])[io];
          acc[rr][0] = fmaf(xv, w0, acc[rr][0]);
          acc[rr][1] = fmaf(xv, w1, acc[rr][1]);
        }
      }
    }
    #pragma unroll
    for (int c = 0; c < 2; ++c) {
      int j = c * 64 + lane;
      if (j < 120) {
        float bs = e_d3_b[j];
        #pragma unroll
        for (int rr = 0; rr < 4; ++rr)
          out[(size_t)(b0 + rr) * kOut + j] = acc[rr][c] + bs;
      }
    }
  }
  __syncthreads();
  {
    float acc[4] = {0.f, 0.f, 0.f, 0.f};
    for (int i = 0; i < kC1; i += 4) {
      float4 v[4];
      #pragma unroll
      for (int rr = 0; rr < 4; ++rr) v[rr] = *reinterpret_cast<const float4*>(BR(rr) + i);
      #pragma unroll
      for (int io = 0; io < 4; ++io) {
        float w0 = b_d1_w[(size_t)(i + io) * 64 + lane];
        #pragma unroll
        for (int rr = 0; rr < 4; ++rr) {
          float xv = reinterpret_cast<const float*>(&v[rr])[io];
          acc[rr] = fmaf(xv, w0, acc[rr]);
        }
      }
    }
    float s  = b_g2[lane] * rsqrtf(b_v2[lane] + EPSBN);
    float t  = b_b2[lane] - b_m2[lane] * s;
    float bs = b_d1_b[lane];
    #pragma unroll
    for (int rr = 0; rr < 4; ++rr)
      AR(rr)[lane] = tanhf(acc[rr] + bs) * s + t;
  }
  __syncthreads();
  {
    const bool m32 = (lane < 32);
    float acc[4] = {0.f, 0.f, 0.f, 0.f};
    for (int i = 0; i < 64; i += 4) {
      float4 v[4];
      #pragma unroll
      for (int rr = 0; rr < 4; ++rr) v[rr] = *reinterpret_cast<const float4*>(AR(rr) + i);
      #pragma unroll
      for (int io = 0; io < 4; ++io) {
        float w0 = m32 ? b_d2_w[(size_t)(i + io) * 32 + lane] : 0.f;
        #pragma unroll
        for (int rr = 0; rr < 4; ++rr) {
          float xv = reinterpret_cast<const float*>(&v[rr])[io];
          acc[rr] = fmaf(xv, w0, acc[rr]);
        }
      }
    }
    if (m32) {
      float bs = b_d2_b[lane];
      #pragma unroll
      for (int rr = 0; rr < 4; ++rr)
        BR(rr)[lane] = tanhf(acc[rr] + bs);
    }
  }
  __syncthreads();
  if (lane < 4) {
    int rr = lane;
    float acc = b_d3_b[0];
    #pragma unroll
    for (int i = 0; i < 32; ++i)
      acc = fmaf(BR(rr)[i], b_d3_w[i], acc);
    out[(size_t)(b0 + rr) * kOut + 120] = 1.f / (1.f + expf(-acc));
  }
  #undef AR
  #undef BR
}

extern "C" void kernel_launch(void* const* d_in, const int* in_sizes, int n_in,
                              void* d_out, int out_size, void* d_ws, size_t ws_size,
                              hipStream_t stream) {
  (void)in_sizes; (void)n_in; (void)out_size;
  const float* p[31];
  for (int i = 0; i < 31; ++i) p[i] = (const float*)d_in[i];
  float* out = (float*)d_out;
  const size_t need = (size_t)BTOT * kC1 * sizeof(float);   // 12.6 MB

  if (ws_size >= need && d_ws != nullptr) {
    float* combined = (float*)d_ws;
    // MEASUREMENT ROUND: conv x3 (idempotent, identical writes) + mlp x1.
    // dur = 3a + m; with R7 (a + m = 382): a = (dur - 382) / 2.
    for (int rep = 0; rep < 3; ++rep) {
      hipLaunchKernelGGL(conv_kernel, dim3(BTOT / 16), dim3(256), 0, stream,
                         p[0], p[1], p[2], combined);
    }
    hipLaunchKernelGGL(mlp_kernel, dim3(BTOT / 4), dim3(64), 0, stream,
                       combined,
                       p[3], p[4], p[5], p[6], p[7], p[8], p[9], p[10], p[11], p[12],
                       p[13], p[14], p[15], p[16], p[17], p[18], p[19], p[20], p[21],
                       p[22], p[23], p[24], p[25], p[26], p[27], p[28], p[29], p[30],
                       out);
  } else {
    hipLaunchKernelGGL(fused_blink_fb, dim3(BTOT / 4), dim3(64), 0, stream,
      p[0], p[1], p[2], p[3], p[4], p[5], p[6], p[7], p[8], p[9],
      p[10], p[11], p[12], p[13], p[14], p[15], p[16], p[17], p[18], p[19],
      p[20], p[21], p[22], p[23], p[24], p[25], p[26], p[27], p[28], p[29], p[30],
      out);
  }
}

// Round 10
// 380.570 us; speedup vs baseline: 2.0198x; 2.0198x over previous
//
#include <hip/hip_runtime.h>
#include <hip/hip_bf16.h>

#define EPSBN 1e-3f

constexpr int kC1  = 192;
constexpr int kN2  = 240;
constexpr int kOut = 121;
constexpr int BTOT = 16384;

// ======================= prep: transpose conv_w -> cwt4[(f*64+w)*4+k] =======================
__global__ __launch_bounds__(256) void prep_cwt(const float* __restrict__ cw,
                                                float* __restrict__ cwt4)
{
  int idx = blockIdx.x * 256 + threadIdx.x;   // f*64 + w, < 7680
  if (idx < 7680) {
    int f = idx >> 6, w = idx & 63;
    float4 v;
    v.x = cw[(size_t)w * 360 + f * 3 + 0];
    v.y = cw[(size_t)w * 360 + f * 3 + 1];
    v.z = cw[(size_t)w * 360 + f * 3 + 2];
    v.w = 0.f;
    *reinterpret_cast<float4*>(cwt4 + (size_t)idx * 4) = v;
  }
}

// ======================= conv v3: lane = w, coalesced row staging =======================
// 1 wave/block, ROWSPB rows/block. Per row: 30 coalesced float4 global loads ->
// LDS f4-transpose xt[fq][65] (pad 65: conflict-free b128 read at lane=w);
// cw read from pre-transposed cwt4 (lane-consecutive b128, L2-hot).
constexpr int ROWSPB = 8;
__global__ __launch_bounds__(64) void conv_kernel3(
    const float* __restrict__ x,
    const float* __restrict__ cwt4, const float* __restrict__ conv_b,
    float* __restrict__ combined)
{
  __shared__ float4 xt[30 * 65];   // 31.2 KB

  const int lane  = threadIdx.x;   // = w
  const int rbase = blockIdx.x * ROWSPB;

  const float bc0 = conv_b[lane * 3 + 0];
  const float bc1 = conv_b[lane * 3 + 1];
  const float bc2 = conv_b[lane * 3 + 2];

  for (int r = 0; r < ROWSPB; ++r) {
    const int row = rbase + r;
    const float* src = x + (size_t)row * 7680;

    // stage row: 1920 floats = 480 f4, 30 per lane, two 15-f4 batches
    {
      float4 v[15];
      #pragma unroll
      for (int i = 0; i < 15; ++i)
        v[i] = *reinterpret_cast<const float4*>(src + 4 * (i * 64 + lane));
      #pragma unroll
      for (int i = 0; i < 15; ++i) {
        int g = i * 64 + lane;
        xt[(g % 30) * 65 + g / 30] = v[i];
      }
      #pragma unroll
      for (int i = 15; i < 30; ++i)
        v[i - 15] = *reinterpret_cast<const float4*>(src + 4 * (i * 64 + lane));
      #pragma unroll
      for (int i = 15; i < 30; ++i) {
        int g = i * 64 + lane;
        xt[(g % 30) * 65 + g / 30] = v[i - 15];
      }
    }
    __syncthreads();

    float a0 = 0.f, a1 = 0.f, a2 = 0.f;
    #pragma unroll 3
    for (int fq = 0; fq < 30; ++fq) {
      float4 x4 = xt[fq * 65 + lane];
      float xs[4] = {x4.x, x4.y, x4.z, x4.w};
      #pragma unroll
      for (int j = 0; j < 4; ++j) {
        int f = 4 * fq + j;
        float4 c4 = *reinterpret_cast<const float4*>(cwt4 + (size_t)(f * 64 + lane) * 4);
        a0 = fmaf(xs[j], c4.x, a0);
        a1 = fmaf(xs[j], c4.y, a1);
        a2 = fmaf(xs[j], c4.z, a2);
      }
    }

    float* dst = combined + (size_t)row * kC1 + 3 * lane;
    dst[0] = tanhf(a0 + bc0);
    dst[1] = tanhf(a1 + bc1);
    dst[2] = tanhf(a2 + bc2);
    __syncthreads();   // xt reads done before next row's writes
  }
}

// ======================= mlp v3: LDS-staged weight k-chunks =======================
// 256 thr = 4 waves x 4 rows = 16 rows/block, grid 1024. Weights streamed
// through wbuf[24][N] (coalesced stage, 2 barriers/chunk); acts in-place Ax.
// 38.4 KB LDS -> 4 blocks/CU = 16 waves/CU.
__global__ __launch_bounds__(256) void mlp_kernel3(
    const float* __restrict__ combined,
    const float* __restrict__ e_g1, const float* __restrict__ e_b1,
    const float* __restrict__ e_m1, const float* __restrict__ e_v1,
    const float* __restrict__ e_d1_w, const float* __restrict__ e_d1_b,
    const float* __restrict__ e_g2, const float* __restrict__ e_b2,
    const float* __restrict__ e_m2, const float* __restrict__ e_v2,
    const float* __restrict__ e_d2_w, const float* __restrict__ e_d2_b,
    const float* __restrict__ e_d3_w, const float* __restrict__ e_d3_b,
    const float* __restrict__ b_g1, const float* __restrict__ b_b1,
    const float* __restrict__ b_m1, const float* __restrict__ b_v1,
    const float* __restrict__ b_d1_w, const float* __restrict__ b_d1_b,
    const float* __restrict__ b_g2, const float* __restrict__ b_b2,
    const float* __restrict__ b_m2, const float* __restrict__ b_v2,
    const float* __restrict__ b_d2_w, const float* __restrict__ b_d2_b,
    const float* __restrict__ b_d3_w, const float* __restrict__ b_d3_b,
    float* __restrict__ out)
{
  __shared__ __align__(16) float Ax[16 * kN2];   // 15.36 KB acts (in place)
  __shared__ float wbuf[24 * kN2];               // 23.04 KB weight chunk

  const int tid  = threadIdx.x;
  const int lane = tid & 63;
  const int wid  = tid >> 6;
  const int r0   = wid * 4;                // wave's local row base
  const int rg   = blockIdx.x * 16;
  #define AXR(rr) (Ax + (size_t)(r0 + (rr)) * kN2)

  // ---- BN_e(combined) -> Ax (own rows; no cross-wave dep) ----
  #pragma unroll
  for (int cc = 0; cc < 3; ++cc) {
    int i = cc * 64 + lane;
    float s = e_g1[i] * rsqrtf(e_v1[i] + EPSBN);
    float t = e_b1[i] - e_m1[i] * s;
    #pragma unroll
    for (int rr = 0; rr < 4; ++rr)
      AXR(rr)[i] = combined[(size_t)(rg + r0 + rr) * kC1 + i] * s + t;
  }

  // ---- eye d1: 192 -> 192, tanh, BN2 (in place) ----
  {
    float acc[4][3] = {};
    for (int k0 = 0; k0 < 192; k0 += 24) {
      __syncthreads();                                    // wbuf free
      for (int e = tid; e < 24 * 192; e += 256)
        wbuf[e] = e_d1_w[(size_t)k0 * 192 + e];
      __syncthreads();                                    // wbuf ready
      #pragma unroll
      for (int i = 0; i < 24; i += 4) {
        float4 v[4];
        #pragma unroll
        for (int rr = 0; rr < 4; ++rr) v[rr] = *reinterpret_cast<const float4*>(AXR(rr) + k0 + i);
        #pragma unroll
        for (int io = 0; io < 4; ++io) {
          float w0 = wbuf[(i + io) * 192 + lane];
          float w1 = wbuf[(i + io) * 192 + 64 + lane];
          float w2 = wbuf[(i + io) * 192 + 128 + lane];
          #pragma unroll
          for (int rr = 0; rr < 4; ++rr) {
            float xv = reinterpret_cast<const float*>(&v[rr])[io];
            acc[rr][0] = fmaf(xv, w0, acc[rr][0]);
            acc[rr][1] = fmaf(xv, w1, acc[rr][1]);
            acc[rr][2] = fmaf(xv, w2, acc[rr][2]);
          }
        }
      }
    }
    #pragma unroll
    for (int c = 0; c < 3; ++c) {
      int j = c * 64 + lane;
      float s  = e_g2[j] * rsqrtf(e_v2[j] + EPSBN);
      float t  = e_b2[j] - e_m2[j] * s;
      float bs = e_d1_b[j];
      #pragma unroll
      for (int rr = 0; rr < 4; ++rr)
        AXR(rr)[j] = tanhf(acc[rr][c] + bs) * s + t;
    }
  }

  // ---- eye d2: 192 -> 240 (in place) ----
  {
    const bool m3 = (lane < 48);
    float acc[4][4] = {};
    for (int k0 = 0; k0 < 192; k0 += 24) {
      __syncthreads();
      for (int e = tid; e < 24 * 240; e += 256)
        wbuf[e] = e_d2_w[(size_t)k0 * 240 + e];
      __syncthreads();
      #pragma unroll
      for (int i = 0; i < 24; i += 4) {
        float4 v[4];
        #pragma unroll
        for (int rr = 0; rr < 4; ++rr) v[rr] = *reinterpret_cast<const float4*>(AXR(rr) + k0 + i);
        #pragma unroll
        for (int io = 0; io < 4; ++io) {
          float w0 = wbuf[(i + io) * 240 + lane];
          float w1 = wbuf[(i + io) * 240 + 64 + lane];
          float w2 = wbuf[(i + io) * 240 + 128 + lane];
          float w3 = m3 ? wbuf[(i + io) * 240 + 192 + lane] : 0.f;
          #pragma unroll
          for (int rr = 0; rr < 4; ++rr) {
            float xv = reinterpret_cast<const float*>(&v[rr])[io];
            acc[rr][0] = fmaf(xv, w0, acc[rr][0]);
            acc[rr][1] = fmaf(xv, w1, acc[rr][1]);
            acc[rr][2] = fmaf(xv, w2, acc[rr][2]);
            acc[rr][3] = fmaf(xv, w3, acc[rr][3]);
          }
        }
      }
    }
    #pragma unroll
    for (int c = 0; c < 4; ++c) {
      int j = c * 64 + lane;
      if (c < 3 || m3) {
        float bs = e_d2_b[j];
        #pragma unroll
        for (int rr = 0; rr < 4; ++rr)
          AXR(rr)[j] = acc[rr][c] + bs;
      }
    }
  }

  // ---- eye d3: 240 -> 120 -> out ----
  {
    const bool m56 = (lane < 56);
    float acc[4][2] = {};
    for (int k0 = 0; k0 < 240; k0 += 24) {
      __syncthreads();
      for (int e = tid; e < 24 * 120; e += 256)
        wbuf[e] = e_d3_w[(size_t)k0 * 120 + e];
      __syncthreads();
      #pragma unroll
      for (int i = 0; i < 24; i += 4) {
        float4 v[4];
        #pragma unroll
        for (int rr = 0; rr < 4; ++rr) v[rr] = *reinterpret_cast<const float4*>(AXR(rr) + k0 + i);
        #pragma unroll
        for (int io = 0; io < 4; ++io) {
          float w0 = wbuf[(i + io) * 120 + lane];
          float w1 = m56 ? wbuf[(i + io) * 120 + 64 + lane] : 0.f;
          #pragma unroll
          for (int rr = 0; rr < 4; ++rr) {
            float xv = reinterpret_cast<const float*>(&v[rr])[io];
            acc[rr][0] = fmaf(xv, w0, acc[rr][0]);
            acc[rr][1] = fmaf(xv, w1, acc[rr][1]);
          }
        }
      }
    }
    #pragma unroll
    for (int c = 0; c < 2; ++c) {
      int j = c * 64 + lane;
      if (j < 120) {
        float bs = e_d3_b[j];
        #pragma unroll
        for (int rr = 0; rr < 4; ++rr)
          out[(size_t)(rg + r0 + rr) * kOut + j] = acc[rr][c] + bs;
      }
    }
  }

  // ---- BN_b(combined) -> Ax (own rows) ----
  #pragma unroll
  for (int cc = 0; cc < 3; ++cc) {
    int i = cc * 64 + lane;
    float s = b_g1[i] * rsqrtf(b_v1[i] + EPSBN);
    float t = b_b1[i] - b_m1[i] * s;
    #pragma unroll
    for (int rr = 0; rr < 4; ++rr)
      AXR(rr)[i] = combined[(size_t)(rg + r0 + rr) * kC1 + i] * s + t;
  }

  // ---- blink d1: 192 -> 64, tanh, BN2 (in place) ----
  {
    float acc[4] = {};
    for (int k0 = 0; k0 < 192; k0 += 24) {
      __syncthreads();
      for (int e = tid; e < 24 * 64; e += 256)
        wbuf[e] = b_d1_w[(size_t)k0 * 64 + e];
      __syncthreads();
      #pragma unroll
      for (int i = 0; i < 24; i += 4) {
        float4 v[4];
        #pragma unroll
        for (int rr = 0; rr < 4; ++rr) v[rr] = *reinterpret_cast<const float4*>(AXR(rr) + k0 + i);
        #pragma unroll
        for (int io = 0; io < 4; ++io) {
          float w0 = wbuf[(i + io) * 64 + lane];
          #pragma unroll
          for (int rr = 0; rr < 4; ++rr) {
            float xv = reinterpret_cast<const float*>(&v[rr])[io];
            acc[rr] = fmaf(xv, w0, acc[rr]);
          }
        }
      }
    }
    float s  = b_g2[lane] * rsqrtf(b_v2[lane] + EPSBN);
    float t  = b_b2[lane] - b_m2[lane] * s;
    float bs = b_d1_b[lane];
    #pragma unroll
    for (int rr = 0; rr < 4; ++rr)
      AXR(rr)[lane] = tanhf(acc[rr] + bs) * s + t;
  }

  // ---- blink d2: 64 -> 32, tanh (in place) ----
  {
    const bool m32 = (lane < 32);
    float acc[4] = {};
    for (int k0 = 0; k0 < 64; k0 += 24) {
      int klen = (64 - k0 < 24) ? (64 - k0) : 24;
      __syncthreads();
      for (int e = tid; e < klen * 32; e += 256)
        wbuf[e] = b_d2_w[(size_t)k0 * 32 + e];
      __syncthreads();
      for (int i = 0; i < klen; i += 4) {
        float4 v[4];
        #pragma unroll
        for (int rr = 0; rr < 4; ++rr) v[rr] = *reinterpret_cast<const float4*>(AXR(rr) + k0 + i);
        #pragma unroll
        for (int io = 0; io < 4; ++io) {
          float w0 = m32 ? wbuf[(i + io) * 32 + lane] : 0.f;
          #pragma unroll
          for (int rr = 0; rr < 4; ++rr) {
            float xv = reinterpret_cast<const float*>(&v[rr])[io];
            acc[rr] = fmaf(xv, w0, acc[rr]);
          }
        }
      }
    }
    if (m32) {
      float bs = b_d2_b[lane];
      #pragma unroll
      for (int rr = 0; rr < 4; ++rr)
        AXR(rr)[lane] = tanhf(acc[rr] + bs);
    }
  }

  // ---- blink d3: 32 -> 1, sigmoid ----
  if (lane < 4) {
    int rr = lane;
    float acc = b_d3_b[0];
    #pragma unroll
    for (int i = 0; i < 32; ++i)
      acc = fmaf(AXR(rr)[i], b_d3_w[i], acc);
    out[(size_t)(rg + r0 + rr) * kOut + 120] = 1.f / (1.f + expf(-acc));
  }
  #undef AXR
}

// ======================= Fallback: round-5 fused kernel (known-correct) =======================
constexpr int CSTR = 193;
__global__ __launch_bounds__(64, 4) void fused_blink_fb(
    const float* __restrict__ x,
    const float* __restrict__ conv_w, const float* __restrict__ conv_b,
    const float* __restrict__ e_g1, const float* __restrict__ e_b1,
    const float* __restrict__ e_m1, const float* __restrict__ e_v1,
    const float* __restrict__ e_d1_w, const float* __restrict__ e_d1_b,
    const float* __restrict__ e_g2, const float* __restrict__ e_b2,
    const float* __restrict__ e_m2, const float* __restrict__ e_v2,
    const float* __restrict__ e_d2_w, const float* __restrict__ e_d2_b,
    const float* __restrict__ e_d3_w, const float* __restrict__ e_d3_b,
    const float* __restrict__ b_g1, const float* __restrict__ b_b1,
    const float* __restrict__ b_m1, const float* __restrict__ b_v1,
    const float* __restrict__ b_d1_w, const float* __restrict__ b_d1_b,
    const float* __restrict__ b_g2, const float* __restrict__ b_b2,
    const float* __restrict__ b_m2, const float* __restrict__ b_v2,
    const float* __restrict__ b_d2_w, const float* __restrict__ b_d2_b,
    const float* __restrict__ b_d3_w, const float* __restrict__ b_d3_b,
    float* __restrict__ out)
{
  __shared__ float comb[4 * CSTR];
  __shared__ __align__(16) float Ab[4 * kN2];
  __shared__ __align__(16) float Bb[4 * kN2];
  const int lane = threadIdx.x;
  const int b0   = blockIdx.x * 4;
  {
    const int rcv = lane >> 4, wloc = lane & 15;
    for (int wc = 0; wc < 4; ++wc) {
      const int w = wc * 16 + wloc;
      const float* xr  = x + ((size_t)(b0 + rcv) * 64 + w) * 120;
      const float* cwp = conv_w + (size_t)w * 360;
      float a0 = 0.f, a1 = 0.f, a2 = 0.f;
      for (int t = 0; t < 30; ++t) {
        float4 xv = *reinterpret_cast<const float4*>(xr + 4 * t);
        float4 c0 = *reinterpret_cast<const float4*>(cwp + 12 * t);
        float4 c1 = *reinterpret_cast<const float4*>(cwp + 12 * t + 4);
        float4 c2 = *reinterpret_cast<const float4*>(cwp + 12 * t + 8);
        a0 += xv.x * c0.x + xv.y * c0.w + xv.z * c1.z + xv.w * c2.y;
        a1 += xv.x * c0.y + xv.y * c1.x + xv.z * c1.w + xv.w * c2.z;
        a2 += xv.x * c0.z + xv.y * c1.y + xv.z * c2.x + xv.w * c2.w;
      }
      comb[rcv * CSTR + 3 * w + 0] = tanhf(a0 + conv_b[3 * w + 0]);
      comb[rcv * CSTR + 3 * w + 1] = tanhf(a1 + conv_b[3 * w + 1]);
      comb[rcv * CSTR + 3 * w + 2] = tanhf(a2 + conv_b[3 * w + 2]);
    }
  }
  __syncthreads();
  #define AR(rr) (Ab + (size_t)(rr) * kN2)
  #define BR(rr) (Bb + (size_t)(rr) * kN2)
  #pragma unroll
  for (int q = 0; q < 12; ++q) {
    int rr = q / 3, cc = q % 3;
    int i = cc * 64 + lane;
    float s = e_g1[i] * rsqrtf(e_v1[i] + EPSBN);
    AR(rr)[i] = comb[rr * CSTR + i] * s + (e_b1[i] - e_m1[i] * s);
  }
  __syncthreads();
  {
    float acc[4][3];
    #pragma unroll
    for (int rr = 0; rr < 4; ++rr) { acc[rr][0]=acc[rr][1]=acc[rr][2]=0.f; }
    for (int i = 0; i < kC1; i += 4) {
      float4 v[4];
      #pragma unroll
      for (int rr = 0; rr < 4; ++rr) v[rr] = *reinterpret_cast<const float4*>(AR(rr) + i);
      #pragma unroll
      for (int io = 0; io < 4; ++io) {
        const float* wp = e_d1_w + (size_t)(i + io) * kC1 + lane;
        float w0 = wp[0], w1 = wp[64], w2 = wp[128];
        #pragma unroll
        for (int rr = 0; rr < 4; ++rr) {
          float xv = reinterpret_cast<const float*>(&v[rr])[io];
          acc[rr][0] = fmaf(xv, w0, acc[rr][0]);
          acc[rr][1] = fmaf(xv, w1, acc[rr][1]);
          acc[rr][2] = fmaf(xv, w2, acc[rr][2]);
        }
      }
    }
    #pragma unroll
    for (int c = 0; c < 3; ++c) {
      int j = c * 64 + lane;
      float s  = e_g2[j] * rsqrtf(e_v2[j] + EPSBN);
      float t  = e_b2[j] - e_m2[j] * s;
      float bs = e_d1_b[j];
      #pragma unroll
      for (int rr = 0; rr < 4; ++rr)
        BR(rr)[j] = tanhf(acc[rr][c] + bs) * s + t;
    }
  }
  __syncthreads();
  {
    const bool m3 = (lane < 48);
    float acc[4][4];
    #pragma unroll
    for (int rr = 0; rr < 4; ++rr) { acc[rr][0]=acc[rr][1]=acc[rr][2]=acc[rr][3]=0.f; }
    for (int i = 0; i < kC1; i += 4) {
      float4 v[4];
      #pragma unroll
      for (int rr = 0; rr < 4; ++rr) v[rr] = *reinterpret_cast<const float4*>(BR(rr) + i);
      #pragma unroll
      for (int io = 0; io < 4; ++io) {
        const float* wp = e_d2_w + (size_t)(i + io) * kN2 + lane;
        float w0 = wp[0], w1 = wp[64], w2 = wp[128];
        float w3 = m3 ? wp[192] : 0.f;
        #pragma unroll
        for (int rr = 0; rr < 4; ++rr) {
          float xv = reinterpret_cast<const float*>(&v[rr])[io];
          acc[rr][0] = fmaf(xv, w0, acc[rr][0]);
          acc[rr][1] = fmaf(xv, w1, acc[rr][1]);
          acc[rr][2] = fmaf(xv, w2, acc[rr][2]);
          acc[rr][3] = fmaf(xv, w3, acc[rr][3]);
        }
      }
    }
    #pragma unroll
    for (int c = 0; c < 4; ++c) {
      int j = c * 64 + lane;
      if (c < 3 || m3) {
        float bs = e_d2_b[j];
        #pragma unroll
        for (int rr = 0; rr < 4; ++rr)
          AR(rr)[j] = acc[rr][c] + bs;
      }
    }
  }
  __syncthreads();
  #pragma unroll
  for (int q = 0; q < 12; ++q) {
    int rr = q / 3, cc = q % 3;
    int i = cc * 64 + lane;
    float s = b_g1[i] * rsqrtf(b_v1[i] + EPSBN);
    BR(rr)[i] = comb[rr * CSTR + i] * s + (b_b1[i] - b_m1[i] * s);
  }
  {
    const bool m56 = (lane < 56);
    float acc[4][2];
    #pragma unroll
    for (int rr = 0; rr < 4; ++rr) { acc[rr][0]=acc[rr][1]=0.f; }
    for (int i = 0; i < kN2; i += 4) {
      float4 v[4];
      #pragma unroll
      for (int rr = 0; rr < 4; ++rr) v[rr] = *reinterpret_cast<const float4*>(AR(rr) + i);
      #pragma unroll
      for (int io = 0; io < 4; ++io) {
        const float* wp = e_d3_w + (size_t)(i + io) * 120 + lane;
        float w0 = wp[0];
        float w1 = m56 ? wp[64] : 0.f;
        #pragma unroll
        for (int rr = 0; rr < 4; ++rr) {
          float xv = reinterpret_cast<const float*>(&v[rr])[io];
          acc[rr][0] = fmaf(xv, w0, acc[rr][0]);
          acc[rr][1] = fmaf(xv, w1, acc[rr][1]);
        }
      }
    }
    #pragma unroll
    for (int c = 0; c < 2; ++c) {
      int j = c * 64 + lane;
      if (j < 120) {
        float bs = e_d3_b[j];
        #pragma unroll
        for (int rr = 0; rr < 4; ++rr)
          out[(size_t)(b0 + rr) * kOut + j] = acc[rr][c] + bs;
      }
    }
  }
  __syncthreads();
  {
    float acc[4] = {0.f, 0.f, 0.f, 0.f};
    for (int i = 0; i < kC1; i += 4) {
      float4 v[4];
      #pragma unroll
      for (int rr = 0; rr < 4; ++rr) v[rr] = *reinterpret_cast<const float4*>(BR(rr) + i);
      #pragma unroll
      for (int io = 0; io < 4; ++io) {
        float w0 = b_d1_w[(size_t)(i + io) * 64 + lane];
        #pragma unroll
        for (int rr = 0; rr < 4; ++rr) {
          float xv = reinterpret_cast<const float*>(&v[rr])[io];
          acc[rr] = fmaf(xv, w0, acc[rr]);
        }
      }
    }
    float s  = b_g2[lane] * rsqrtf(b_v2[lane] + EPSBN);
    float t  = b_b2[lane] - b_m2[lane] * s;
    float bs = b_d1_b[lane];
    #pragma unroll
    for (int rr = 0; rr < 4; ++rr)
      AR(rr)[lane] = tanhf(acc[rr] + bs) * s + t;
  }
  __syncthreads();
  {
    const bool m32 = (lane < 32);
    float acc[4] = {0.f, 0.f, 0.f, 0.f};
    for (int i = 0; i < 64; i += 4) {
      float4 v[4];
      #pragma unroll
      for (int rr = 0; rr < 4; ++rr) v[rr] = *reinterpret_cast<const float4*>(AR(rr) + i);
      #pragma unroll
      for (int io = 0; io < 4; ++io) {
        float w0 = m32 ? b_d2_w[(size_t)(i + io) * 32 + lane] : 0.f;
        #pragma unroll
        for (int rr = 0; rr < 4; ++rr) {
          float xv = reinterpret_cast<const float*>(&v[rr])[io];
          acc[rr] = fmaf(xv, w0, acc[rr]);
        }
      }
    }
    if (m32) {
      float bs = b_d2_b[lane];
      #pragma unroll
      for (int rr = 0; rr < 4; ++rr)
        BR(rr)[lane] = tanhf(acc[rr] + bs);
    }
  }
  __syncthreads();
  if (lane < 4) {
    int rr = lane;
    float acc = b_d3_b[0];
    #pragma unroll
    for (int i = 0; i < 32; ++i)
      acc = fmaf(BR(rr)[i], b_d3_w[i], acc);
    out[(size_t)(b0 + rr) * kOut + 120] = 1.f / (1.f + expf(-acc));
  }
  #undef AR
  #undef BR
}

extern "C" void kernel_launch(void* const* d_in, const int* in_sizes, int n_in,
                              void* d_out, int out_size, void* d_ws, size_t ws_size,
                              hipStream_t stream) {
  (void)in_sizes; (void)n_in; (void)out_size;
  const float* p[31];
  for (int i = 0; i < 31; ++i) p[i] = (const float*)d_in[i];
  float* out = (float*)d_out;
  const size_t combined_elems = (size_t)BTOT * kC1;            // 3,145,728
  const size_t need = (combined_elems + 30720) * sizeof(float); // 12.7 MB

  if (ws_size >= need && d_ws != nullptr) {
    float* combined = (float*)d_ws;
    float* cwt4     = combined + combined_elems;
    hipLaunchKernelGGL(prep_cwt, dim3(30), dim3(256), 0, stream, p[1], cwt4);
    hipLaunchKernelGGL(conv_kernel3, dim3(BTOT / ROWSPB), dim3(64), 0, stream,
                       p[0], cwt4, p[2], combined);
    hipLaunchKernelGGL(mlp_kernel3, dim3(BTOT / 16), dim3(256), 0, stream,
                       combined,
                       p[3], p[4], p[5], p[6], p[7], p[8], p[9], p[10], p[11], p[12],
                       p[13], p[14], p[15], p[16], p[17], p[18], p[19], p[20], p[21],
                       p[22], p[23], p[24], p[25], p[26], p[27], p[28], p[29], p[30],
                       out);
  } else {
    hipLaunchKernelGGL(fused_blink_fb, dim3(BTOT / 4), dim3(64), 0, stream,
      p[0], p[1], p[2], p[3], p[4], p[5], p[6], p[7], p[8], p[9],
      p[10], p[11], p[12], p[13], p[14], p[15], p[16], p[17], p[18], p[19],
      p[20], p[21], p[22], p[23], p[24], p[25], p[26], p[27], p[28], p[29], p[30],
      out);
  }
}